// Round 15
// baseline (113.455 us; speedup 1.0000x reference)
//
#include <hip/hip_runtime.h>
#include <hip/hip_bf16.h>
#include <math.h>

// Shapes
#define QL 32768
#define DD 1024
#define NTOK 64

using short8   = __attribute__((ext_vector_type(8))) short;
using f32x4    = __attribute__((ext_vector_type(4))) float;
using float4v  = __attribute__((ext_vector_type(4))) float;
using ushort4v = __attribute__((ext_vector_type(4))) unsigned short;

// RNE f32->bf16 via bit trick (exact RNE)
__device__ __forceinline__ unsigned short f2bf(float f) {
    unsigned int u = __float_as_uint(f);
    unsigned int r = (u + 0x7FFFu + ((u >> 16) & 1u)) >> 16;
    return (unsigned short)r;
}

__device__ __forceinline__ short8 pack_bf16x8(float4v lo, float4v hi) {
    short8 a;
    ((__hip_bfloat162*)&a)[0] = __float22bfloat162_rn(float2{lo.x, lo.y});
    ((__hip_bfloat162*)&a)[1] = __float22bfloat162_rn(float2{lo.z, lo.w});
    ((__hip_bfloat162*)&a)[2] = __float22bfloat162_rn(float2{hi.x, hi.y});
    ((__hip_bfloat162*)&a)[3] = __float22bfloat162_rn(float2{hi.z, hi.w});
    return a;
}

// ---------------------------------------------------------------------------
// Prologue 1 (verified r13): transpose-convert Wq -> WqT bf16, Pv -> PvT bf16.
// ---------------------------------------------------------------------------
__global__ __launch_bounds__(256) void prep_transpose_kernel(
        const float* __restrict__ Wq, const float* __restrict__ Pv,
        unsigned short* __restrict__ WqT, unsigned short* __restrict__ PvT) {
    __shared__ float tile[64][65];
    int b = blockIdx.x;
    const float* src; unsigned short* dst; int R, C, r0, c0;
    if (b < 256) { src = Wq; dst = WqT; R = 1024; C = 1024;
                   r0 = (b >> 4) << 6; c0 = (b & 15) << 6; }
    else         { b -= 256; src = Pv; dst = PvT; R = 64; C = 1024;
                   r0 = 0; c0 = b << 6; }
    const int tid = threadIdx.x;
#pragma unroll
    for (int i = 0; i < 16; ++i) {
        const int lin = tid + 256 * i;
        const int row = lin >> 6, col = lin & 63;
        if (r0 + row < R)
            tile[row][col] = src[(size_t)(r0 + row) * C + c0 + col];
    }
    __syncthreads();
#pragma unroll
    for (int i = 0; i < 16; ++i) {
        const int lin = tid + 256 * i;
        const int row = lin >> 6, col = lin & 63;
        if (r0 + col < R)
            dst[(size_t)(c0 + row) * R + r0 + col] = f2bf(tile[col][row]);
    }
}

// ---------------------------------------------------------------------------
// Prologue 2 (verified r13): Kp = Pk @ Wq via bf16 MFMA (B from WqT).
// grid 64 x 256: block b owns d-cols b*16..b*16+16.
// ---------------------------------------------------------------------------
__global__ __launch_bounds__(256) void kp_mfma_kernel(
        const float* __restrict__ Pk, const unsigned short* __restrict__ WqT,
        unsigned short* __restrict__ Kp) {
    const int tid = threadIdx.x;
    const int w   = tid >> 6;
    const int l   = tid & 63;
    const int lhi = l >> 4;
    const int llo = l & 15;
    const int N0  = blockIdx.x * 16;

    f32x4 acc = (f32x4){0.f, 0.f, 0.f, 0.f};

    for (int kb = 0; kb < 32; ++kb) {
        const int k0 = kb * 32 + lhi * 8;
        float4v p0 = *(const float4v*)(Pk + (size_t)(w * 16 + llo) * DD + k0);
        float4v p1 = *(const float4v*)(Pk + (size_t)(w * 16 + llo) * DD + k0 + 4);
        short8 a = pack_bf16x8(p0, p1);
        short8 b = *(const short8*)(WqT + (size_t)(N0 + llo) * DD + k0);
        acc = __builtin_amdgcn_mfma_f32_16x16x32_bf16(a, b, acc, 0, 0, 0);
    }
#pragma unroll
    for (int j = 0; j < 4; ++j) {
        const int t = w * 16 + lhi * 4 + j;
        Kp[(size_t)t * DD + N0 + llo] = f2bf(acc[j]);
    }
}

// ---------------------------------------------------------------------------
// Main: fully wave-autonomous, ZERO barriers. grid 512 x 256 (4 waves).
// Each wave owns 16 q-rows end-to-end:
//   QK^T: 16 K-steps of 64; 2-generation REGISTER pipeline; per step
//     12 loads (4x x-dwordx4 wave-coalesced + 8x Kp-frag from L2);
//     counted s_waitcnt vmcnt(12) per step (wave-local; no s_barrier).
//   Norm: in-wave shfl_xor over llo lanes -> l2-norm*8 -> exact GELU.
//   Transpose: per-wave 2 KB LDS (swizzled chunk XOR row&7), wave-local.
//   PV: y = s' @ Pv swapped MFMA (D[m=d][n=q]); PvT frags from L2;
//     float4 stores. 64 d-tiles.
// Waves desync naturally -> read & write streams overlap chip-wide.
// ---------------------------------------------------------------------------
__global__ __launch_bounds__(256) void pattn_kernel(
        const float* __restrict__ x, const unsigned short* __restrict__ Kp,
        const unsigned short* __restrict__ PvT, float* __restrict__ out) {
    __shared__ __align__(16) unsigned char sPall[8192];   // 2 KB per wave
    const int tid = threadIdx.x;
    const int w   = tid >> 6;
    const int l   = tid & 63;
    const int lhi = l >> 4;     // 0..3
    const int llo = l & 15;     // 0..15
    const int R0  = (blockIdx.x * 4 + w) * 16;
    unsigned char* sP = sPall + w * 2048;

    const float* xrow = x + (size_t)(R0 + llo) * DD;   // this lane's A row

    f32x4 acc[4];
#pragma unroll
    for (int ct = 0; ct < 4; ++ct) acc[ct] = (f32x4){0.f, 0.f, 0.f, 0.f};

    float4v aR[2][4];
    short8  bR[2][8];

    // 12 loads per generation: 4 x-dwordx4 + 8 Kp-frag dwordx4
#define LOADG(t, g)                                                             \
    {                                                                           \
        const int k0 = (t) * 64 + lhi * 8;                                      \
        aR[g][0] = *(const float4v*)(xrow + k0);                                \
        aR[g][1] = *(const float4v*)(xrow + k0 + 4);                            \
        aR[g][2] = *(const float4v*)(xrow + k0 + 32);                           \
        aR[g][3] = *(const float4v*)(xrow + k0 + 36);                           \
        _Pragma("unroll")                                                       \
        for (int ct = 0; ct < 4; ++ct) {                                        \
            const unsigned short* kp_ = Kp + (size_t)(ct * 16 + llo) * DD + (t) * 64 + lhi * 8; \
            bR[g][ct]     = *(const short8*)(kp_);                              \
            bR[g][4 + ct] = *(const short8*)(kp_ + 32);                         \
        }                                                                       \
    }

#define COMP(t, g)                                                              \
    {                                                                           \
        _Pragma("unroll")                                                       \
        for (int ks = 0; ks < 2; ++ks) {                                        \
            const short8 a = pack_bf16x8(aR[g][ks * 2], aR[g][ks * 2 + 1]);     \
            _Pragma("unroll")                                                   \
            for (int ct = 0; ct < 4; ++ct)                                      \
                acc[ct] = __builtin_amdgcn_mfma_f32_16x16x32_bf16(              \
                              a, bR[g][ks * 4 + ct], acc[ct], 0, 0, 0);         \
        }                                                                       \
    }

    LOADG(0, 0);
    LOADG(1, 1);
#pragma unroll
    for (int t = 0; t < 16; ++t) {
        if (t < 15) { asm volatile("s_waitcnt vmcnt(12)" ::: "memory"); }
        else        { asm volatile("s_waitcnt vmcnt(0)"  ::: "memory"); }
        __builtin_amdgcn_sched_barrier(0);
        COMP(t, t & 1);
        if (t < 14) LOADG(t + 2, t & 1);
    }
#undef LOADG
#undef COMP

    // ---- in-wave row l2-norm*8 + exact GELU -> sP (bf16, swizzled) ----
    // acc[ct][j]: row = lhi*4+j, token = ct*16+llo
    float scl[4];
#pragma unroll
    for (int j = 0; j < 4; ++j) {
        float ssq = acc[0][j] * acc[0][j] + acc[1][j] * acc[1][j]
                  + acc[2][j] * acc[2][j] + acc[3][j] * acc[3][j];
        ssq += __shfl_xor(ssq, 1);
        ssq += __shfl_xor(ssq, 2);
        ssq += __shfl_xor(ssq, 4);
        ssq += __shfl_xor(ssq, 8);
        scl[j] = 8.0f / sqrtf(ssq);
    }
#pragma unroll
    for (int ct = 0; ct < 4; ++ct)
#pragma unroll
        for (int j = 0; j < 4; ++j) {
            const float v = acc[ct][j] * scl[j];
            const float g = 0.5f * v * (1.0f + erff(v * 0.70710678118654752f));
            const int row = lhi * 4 + j;
            const int tok = ct * 16 + llo;
            const int off = row * 128 + (((tok >> 3) ^ (row & 7)) << 4) + (tok & 7) * 2;
            *(unsigned short*)(sP + off) = f2bf(g);
        }
    // wave-local LDS dependency: compiler inserts lgkmcnt ordering below.

    // ---- PV: y[16 rows][1024] = s' @ Pv; swapped MFMA; float4 stores ----
    const short8 sb0 = *(const short8*)(sP + llo * 128 + (((lhi)     ^ (llo & 7)) << 4));
    const short8 sb1 = *(const short8*)(sP + llo * 128 + (((4 + lhi) ^ (llo & 7)) << 4));
    float* orow = out + (size_t)(R0 + llo) * DD + lhi * 4;
#pragma unroll 4
    for (int dt = 0; dt < 64; ++dt) {
        const unsigned short* ap = PvT + (size_t)(dt * 16 + llo) * 64 + lhi * 8;
        const short8 pa0 = *(const short8*)ap;
        const short8 pa1 = *(const short8*)(ap + 32);
        f32x4 c2 = (f32x4){0.f, 0.f, 0.f, 0.f};
        c2 = __builtin_amdgcn_mfma_f32_16x16x32_bf16(pa0, sb0, c2, 0, 0, 0);
        c2 = __builtin_amdgcn_mfma_f32_16x16x32_bf16(pa1, sb1, c2, 0, 0, 0);
        *(float4v*)(orow + dt * 16) = c2;
    }
}

// ---------------------------------------------------------------------------
extern "C" void kernel_launch(void* const* d_in, const int* in_sizes, int n_in,
                              void* d_out, int out_size, void* d_ws, size_t ws_size,
                              hipStream_t stream) {
    (void)in_sizes; (void)n_in; (void)out_size; (void)ws_size;
    const float* x  = (const float*)d_in[0];
    const float* Wq = (const float*)d_in[1];
    const float* Pk = (const float*)d_in[2];
    const float* Pv = (const float*)d_in[3];
    float* out = (float*)d_out;

    // ws layout (2.25 MB total):
    //   WqT bf16 [1024][1024] @ 0            (2 MB)
    //   Kp  bf16 [64][1024]   @ 2 MB         (128 KB)
    //   PvT bf16 [1024][64]   @ 2 MB + 128K  (128 KB)
    unsigned short* WqT = (unsigned short*)d_ws;
    unsigned short* Kp  = (unsigned short*)((char*)d_ws + 2097152);
    unsigned short* PvT = (unsigned short*)((char*)d_ws + 2097152 + 131072);

    prep_transpose_kernel<<<272, 256, 0, stream>>>(Wq, Pv, WqT, PvT);
    kp_mfma_kernel<<<64, 256, 0, stream>>>(Pk, WqT, Kp);
    pattn_kernel<<<512, 256, 0, stream>>>(x, Kp, PvT, out);
}

// Round 16
// 100.733 us; speedup vs baseline: 1.1263x; 1.1263x over previous
//
#include <hip/hip_runtime.h>
#include <hip/hip_bf16.h>
#include <math.h>

// Shapes
#define QL 32768
#define DD 1024
#define NTOK 64

using short8   = __attribute__((ext_vector_type(8))) short;
using f32x4    = __attribute__((ext_vector_type(4))) float;
using float4v  = __attribute__((ext_vector_type(4))) float;
using ushort4v = __attribute__((ext_vector_type(4))) unsigned short;

// RNE f32->bf16 via bit trick (exact RNE)
__device__ __forceinline__ unsigned short f2bf(float f) {
    unsigned int u = __float_as_uint(f);
    unsigned int r = (u + 0x7FFFu + ((u >> 16) & 1u)) >> 16;
    return (unsigned short)r;
}

__device__ __forceinline__ short8 pack_bf16x8(float4v lo, float4v hi) {
    short8 a;
    ((__hip_bfloat162*)&a)[0] = __float22bfloat162_rn(float2{lo.x, lo.y});
    ((__hip_bfloat162*)&a)[1] = __float22bfloat162_rn(float2{lo.z, lo.w});
    ((__hip_bfloat162*)&a)[2] = __float22bfloat162_rn(float2{hi.x, hi.y});
    ((__hip_bfloat162*)&a)[3] = __float22bfloat162_rn(float2{hi.z, hi.w});
    return a;
}

// async global->LDS, 16B per lane; dest = wave-uniform base + lane*16
__device__ __forceinline__ void gload_lds16(const void* g, void* l) {
    __builtin_amdgcn_global_load_lds(
        (const __attribute__((address_space(1))) void*)g,
        (__attribute__((address_space(3))) void*)l,
        16, 0, 0);
}

// ---------------------------------------------------------------------------
// Prologue 1 (verified): transpose-convert Wq -> WqT bf16, Pv -> PvT bf16.
// ---------------------------------------------------------------------------
__global__ __launch_bounds__(256) void prep_transpose_kernel(
        const float* __restrict__ Wq, const float* __restrict__ Pv,
        unsigned short* __restrict__ WqT, unsigned short* __restrict__ PvT) {
    __shared__ float tile[64][65];
    int b = blockIdx.x;
    const float* src; unsigned short* dst; int R, C, r0, c0;
    if (b < 256) { src = Wq; dst = WqT; R = 1024; C = 1024;
                   r0 = (b >> 4) << 6; c0 = (b & 15) << 6; }
    else         { b -= 256; src = Pv; dst = PvT; R = 64; C = 1024;
                   r0 = 0; c0 = b << 6; }
    const int tid = threadIdx.x;
#pragma unroll
    for (int i = 0; i < 16; ++i) {
        const int lin = tid + 256 * i;
        const int row = lin >> 6, col = lin & 63;
        if (r0 + row < R)
            tile[row][col] = src[(size_t)(r0 + row) * C + c0 + col];
    }
    __syncthreads();
#pragma unroll
    for (int i = 0; i < 16; ++i) {
        const int lin = tid + 256 * i;
        const int row = lin >> 6, col = lin & 63;
        if (r0 + col < R)
            dst[(size_t)(c0 + row) * R + r0 + col] = f2bf(tile[col][row]);
    }
}

// ---------------------------------------------------------------------------
// Prologue 2 (verified r13): Kp = Pk @ Wq via bf16 MFMA. grid 64 x 256.
// ---------------------------------------------------------------------------
__global__ __launch_bounds__(256) void kp_mfma_kernel(
        const float* __restrict__ Pk, const unsigned short* __restrict__ WqT,
        unsigned short* __restrict__ Kp) {
    const int tid = threadIdx.x;
    const int w   = tid >> 6;
    const int l   = tid & 63;
    const int lhi = l >> 4;
    const int llo = l & 15;
    const int N0  = blockIdx.x * 16;

    f32x4 acc = (f32x4){0.f, 0.f, 0.f, 0.f};

    for (int kb = 0; kb < 32; ++kb) {
        const int k0 = kb * 32 + lhi * 8;
        float4v p0 = *(const float4v*)(Pk + (size_t)(w * 16 + llo) * DD + k0);
        float4v p1 = *(const float4v*)(Pk + (size_t)(w * 16 + llo) * DD + k0 + 4);
        short8 a = pack_bf16x8(p0, p1);
        short8 b = *(const short8*)(WqT + (size_t)(N0 + llo) * DD + k0);
        acc = __builtin_amdgcn_mfma_f32_16x16x32_bf16(a, b, acc, 0, 0, 0);
    }
#pragma unroll
    for (int j = 0; j < 4; ++j) {
        const int t = w * 16 + lhi * 4 + j;
        Kp[(size_t)t * DD + N0 + llo] = f2bf(acc[j]);
    }
}

// ---------------------------------------------------------------------------
// Fused main (r10 structure + phase-C fixes): 256 blocks x 512 thr (8 waves),
// 128 q-rows/block, 1 block/CU.
// Phase A (r10 verbatim): 16 K-steps of 64; 3-deep circular gload_lds bufs
//   (A 32 KB + B 8 KB per step); counted vmcnt(5) + raw s_barrier.
// Preload: all 16 PvT frags -> 64 VGPRs right after phase A (latency hidden
//   under phase B), pinned with sched_barrier against sinking.
// Phase B (r10 verbatim): reduce in sSf alias -> l2-norm*8 -> exact GELU ->
//   s' bf16 [128][128B] swizzled at smem+98304.
// Phase C (new): per qb-tile: 16 MFMA (no VMEM reads) -> wave-local padded
//   LDS cbuf [16][132] f32 -> readback mapped to FULL-LINE stores
//   (8 rows x 128 B contiguous per instruction). Zero new barriers.
// ---------------------------------------------------------------------------
__global__ __launch_bounds__(512) void pattn_kernel(
        const float* __restrict__ x, const unsigned short* __restrict__ Kp,
        const unsigned short* __restrict__ PvT, float* __restrict__ out) {
    __shared__ __align__(16) unsigned char smem[122880];   // 3*32K (A) + 3*8K (B)

    const int tid = threadIdx.x;
    const int w   = tid >> 6;     // 0..7
    const int l   = tid & 63;
    const int lhi = l >> 4;       // 0..3
    const int llo = l & 15;       // 0..15
    const int wr  = w >> 2;       // 0..1  row-half
    const int wt  = w & 3;        // 0..3  token-slice
    const int R0  = blockIdx.x * 128;
    const char* xb  = (const char*)x;
    const char* kpb = (const char*)Kp;

    f32x4 acc[4];
#pragma unroll
    for (int rf = 0; rf < 4; ++rf) acc[rf] = (f32x4){0.f, 0.f, 0.f, 0.f};

#define ABUF(t) (smem + ((t) % 3) * 32768)
#define BBUF(t) (smem + 98304 + ((t) % 3) * 8192)

#define STAGE(t)                                                                \
    {                                                                           \
        unsigned char* abuf = ABUF(t);                                          \
        unsigned char* bbuf = BBUF(t);                                          \
        _Pragma("unroll")                                                       \
        for (int i = 0; i < 4; ++i) {                                           \
            const int row = i * 32 + w * 4 + (l >> 4);                          \
            const int csw = (l & 15) ^ ((row & 7) << 1);                        \
            gload_lds16(xb + (size_t)(R0 + row) * 4096 + (t) * 256 + csw * 16,  \
                        (void*)(abuf + (i * 32 + w * 4) * 256));                \
        }                                                                       \
        const int brow = w * 8 + (l >> 3);                                      \
        const int bcs  = (l & 7) ^ (brow & 7);                                  \
        gload_lds16(kpb + (size_t)brow * 2048 + (t) * 128 + bcs * 16,           \
                    (void*)(bbuf + (w * 8) * 128));                             \
    }

#define COMPUTE(t)                                                              \
    {                                                                           \
        unsigned char* abuf = ABUF(t);                                          \
        unsigned char* bbuf = BBUF(t);                                          \
        _Pragma("unroll")                                                       \
        for (int ks = 0; ks < 2; ++ks) {                                        \
            const int btok = wt * 16 + llo;                                     \
            const short8 bfrg = *(const short8*)(bbuf + btok * 128 +            \
                                  (((ks * 4 + lhi) ^ (btok & 7)) << 4));        \
            _Pragma("unroll")                                                   \
            for (int rf = 0; rf < 4; ++rf) {                                    \
                const int arow  = wr * 64 + rf * 16 + llo;                      \
                const int abyte = arow * 256 +                                  \
                                  (((ks * 4 + lhi) ^ (arow & 7)) << 5);         \
                const float4v f0 = *(const float4v*)(abuf + abyte);             \
                const float4v f1 = *(const float4v*)(abuf + abyte + 16);        \
                short8 a = pack_bf16x8(f0, f1);                                 \
                acc[rf] = __builtin_amdgcn_mfma_f32_16x16x32_bf16(a, bfrg, acc[rf], 0, 0, 0); \
            }                                                                   \
        }                                                                       \
    }

    // ---- Phase A: depth-3 pipeline, 2-step lookahead, counted vmcnt ----
    STAGE(0); STAGE(1);
#pragma unroll
    for (int t = 0; t < 16; ++t) {
        if (t < 15) { asm volatile("s_waitcnt vmcnt(5)" ::: "memory"); }
        else        { asm volatile("s_waitcnt vmcnt(0)" ::: "memory"); }
        __builtin_amdgcn_s_barrier();
        __builtin_amdgcn_sched_barrier(0);
        if (t < 14) STAGE(t + 2);
        COMPUTE(t);
    }
#undef STAGE
#undef COMPUTE
#undef ABUF
#undef BBUF

    __syncthreads();   // pipeline fully retired -> LDS free for aliases

    // ---- PvT preload: 16 frags -> 64 VGPRs; latency hides under phase B ----
    const int d0 = w * 128;
    short8 pa0[8], pa1[8];
#pragma unroll
    for (int dt = 0; dt < 8; ++dt) {
        const unsigned short* ap = PvT + (size_t)(d0 + dt * 16 + llo) * 64 + lhi * 8;
        pa0[dt] = *(const short8*)ap;
        pa1[dt] = *(const short8*)(ap + 32);
    }
    __builtin_amdgcn_sched_barrier(0);   // pin: do not sink these loads

    // ---- Phase B: partials -> sSf, 4-lane norm, exact GELU -> sP ----
    float (*sSf)[68] = (float (*)[68])(void*)smem;          // [128][68] f32, 34.8 KB
#pragma unroll
    for (int rf = 0; rf < 4; ++rf)
#pragma unroll
        for (int j = 0; j < 4; ++j)
            sSf[wr * 64 + rf * 16 + lhi * 4 + j][wt * 16 + llo] = acc[rf][j];
    __syncthreads();

    unsigned char* sP = smem + 98304;                       // s' [128][128B] swizzled
    {
        const int r  = tid >> 2;          // 0..127 q-row
        const int tq = tid & 3;           // 16-token slice
        const f32x4 v0 = *(const f32x4*)&sSf[r][tq * 16];
        const f32x4 v1 = *(const f32x4*)&sSf[r][tq * 16 + 4];
        const f32x4 v2 = *(const f32x4*)&sSf[r][tq * 16 + 8];
        const f32x4 v3 = *(const f32x4*)&sSf[r][tq * 16 + 12];
        float ssq = v0.x*v0.x + v0.y*v0.y + v0.z*v0.z + v0.w*v0.w
                  + v1.x*v1.x + v1.y*v1.y + v1.z*v1.z + v1.w*v1.w
                  + v2.x*v2.x + v2.y*v2.y + v2.z*v2.z + v2.w*v2.w
                  + v3.x*v3.x + v3.y*v3.y + v3.z*v3.z + v3.w*v3.w;
        ssq += __shfl_xor(ssq, 1);
        ssq += __shfl_xor(ssq, 2);
        const float scale = 8.0f / sqrtf(ssq);
        short8 g0, g1;
#pragma unroll
        for (int k = 0; k < 4; ++k) {
            const float a0 = v0[k] * scale, a1 = v1[k] * scale;
            const float a2 = v2[k] * scale, a3 = v3[k] * scale;
            g0[k]     = (short)f2bf(0.5f * a0 * (1.0f + erff(a0 * 0.70710678118654752f)));
            g0[4 + k] = (short)f2bf(0.5f * a1 * (1.0f + erff(a1 * 0.70710678118654752f)));
            g1[k]     = (short)f2bf(0.5f * a2 * (1.0f + erff(a2 * 0.70710678118654752f)));
            g1[4 + k] = (short)f2bf(0.5f * a3 * (1.0f + erff(a3 * 0.70710678118654752f)));
        }
        *(short8*)(sP + r * 128 + (((2 * tq)     ^ (r & 7)) << 4)) = g0;
        *(short8*)(sP + r * 128 + (((2 * tq + 1) ^ (r & 7)) << 4)) = g1;
    }
    __syncthreads();

    // ---- Phase C: MFMA (no VMEM) -> wave-local cbuf -> full-line stores ----
    short8 sfr[8][2];
#pragma unroll
    for (int qb = 0; qb < 8; ++qb) {
        const int q = qb * 16 + llo;
        sfr[qb][0] = *(const short8*)(sP + q * 128 + (((lhi)     ^ (q & 7)) << 4));
        sfr[qb][1] = *(const short8*)(sP + q * 128 + (((4 + lhi) ^ (q & 7)) << 4));
    }

    float* cbuf = (float*)(smem + w * 8704);    // [16 q][132 d] f32, wave-local
#pragma unroll 1
    for (int qb = 0; qb < 8; ++qb) {
#pragma unroll
        for (int dt = 0; dt < 8; ++dt) {
            f32x4 c2 = (f32x4){0.f, 0.f, 0.f, 0.f};
            c2 = __builtin_amdgcn_mfma_f32_16x16x32_bf16(pa0[dt], sfr[qb][0], c2, 0, 0, 0);
            c2 = __builtin_amdgcn_mfma_f32_16x16x32_bf16(pa1[dt], sfr[qb][1], c2, 0, 0, 0);
            // lane: q=llo, d-block dt*16 + lhi*4 .. +4
            *(f32x4*)(cbuf + llo * 132 + dt * 16 + lhi * 4) = c2;
        }
        // readback + store: 8 instrs, each 8 rows x 128 B contiguous (full lines)
#pragma unroll
        for (int qh = 0; qh < 2; ++qh)
#pragma unroll
            for (int i = 0; i < 4; ++i) {
                const int r = qh * 8 + (l >> 3);
                const int c = (l & 7) * 4 + i * 32;
                const f32x4 v = *(const f32x4*)(cbuf + r * 132 + c);
                *(float4v*)(out + (size_t)(R0 + qb * 16 + r) * DD + d0 + c) = v;
            }
    }
}

// ---------------------------------------------------------------------------
extern "C" void kernel_launch(void* const* d_in, const int* in_sizes, int n_in,
                              void* d_out, int out_size, void* d_ws, size_t ws_size,
                              hipStream_t stream) {
    (void)in_sizes; (void)n_in; (void)out_size; (void)ws_size;
    const float* x  = (const float*)d_in[0];
    const float* Wq = (const float*)d_in[1];
    const float* Pk = (const float*)d_in[2];
    const float* Pv = (const float*)d_in[3];
    float* out = (float*)d_out;

    // ws layout (2.25 MB total):
    //   WqT bf16 [1024][1024] @ 0            (2 MB)
    //   Kp  bf16 [64][1024]   @ 2 MB         (128 KB)
    //   PvT bf16 [1024][64]   @ 2 MB + 128K  (128 KB)
    unsigned short* WqT = (unsigned short*)d_ws;
    unsigned short* Kp  = (unsigned short*)((char*)d_ws + 2097152);
    unsigned short* PvT = (unsigned short*)((char*)d_ws + 2097152 + 131072);

    prep_transpose_kernel<<<272, 256, 0, stream>>>(Wq, Pv, WqT, PvT);
    kp_mfma_kernel<<<64, 256, 0, stream>>>(Pk, WqT, Kp);
    pattn_kernel<<<256, 512, 0, stream>>>(x, Kp, PvT, out);
}

// Round 17
// 70.626 us; speedup vs baseline: 1.6064x; 1.4263x over previous
//
#include <hip/hip_runtime.h>
#include <hip/hip_bf16.h>
#include <math.h>

// Shapes
#define QL 32768
#define DD 1024
#define NTOK 64

using short8   = __attribute__((ext_vector_type(8))) short;
using f32x4    = __attribute__((ext_vector_type(4))) float;
using float4v  = __attribute__((ext_vector_type(4))) float;
using ushort4v = __attribute__((ext_vector_type(4))) unsigned short;

// RNE f32->bf16 via bit trick (exact RNE)
__device__ __forceinline__ unsigned short f2bf(float f) {
    unsigned int u = __float_as_uint(f);
    unsigned int r = (u + 0x7FFFu + ((u >> 16) & 1u)) >> 16;
    return (unsigned short)r;
}

__device__ __forceinline__ short8 pack_bf16x8(float4v lo, float4v hi) {
    short8 a;
    ((__hip_bfloat162*)&a)[0] = __float22bfloat162_rn(float2{lo.x, lo.y});
    ((__hip_bfloat162*)&a)[1] = __float22bfloat162_rn(float2{lo.z, lo.w});
    ((__hip_bfloat162*)&a)[2] = __float22bfloat162_rn(float2{hi.x, hi.y});
    ((__hip_bfloat162*)&a)[3] = __float22bfloat162_rn(float2{hi.z, hi.w});
    return a;
}

// async global->LDS, 16B per lane; dest = wave-uniform base + lane*16
__device__ __forceinline__ void gload_lds16(const void* g, void* l) {
    __builtin_amdgcn_global_load_lds(
        (const __attribute__((address_space(1))) void*)g,
        (__attribute__((address_space(3))) void*)l,
        16, 0, 0);
}

// ---------------------------------------------------------------------------
// Prologue 1 (verified): transpose-convert Wq -> WqT bf16, Pv -> PvT bf16.
// ---------------------------------------------------------------------------
__global__ __launch_bounds__(256) void prep_transpose_kernel(
        const float* __restrict__ Wq, const float* __restrict__ Pv,
        unsigned short* __restrict__ WqT, unsigned short* __restrict__ PvT) {
    __shared__ float tile[64][65];
    int b = blockIdx.x;
    const float* src; unsigned short* dst; int R, C, r0, c0;
    if (b < 256) { src = Wq; dst = WqT; R = 1024; C = 1024;
                   r0 = (b >> 4) << 6; c0 = (b & 15) << 6; }
    else         { b -= 256; src = Pv; dst = PvT; R = 64; C = 1024;
                   r0 = 0; c0 = b << 6; }
    const int tid = threadIdx.x;
#pragma unroll
    for (int i = 0; i < 16; ++i) {
        const int lin = tid + 256 * i;
        const int row = lin >> 6, col = lin & 63;
        if (r0 + row < R)
            tile[row][col] = src[(size_t)(r0 + row) * C + c0 + col];
    }
    __syncthreads();
#pragma unroll
    for (int i = 0; i < 16; ++i) {
        const int lin = tid + 256 * i;
        const int row = lin >> 6, col = lin & 63;
        if (r0 + col < R)
            dst[(size_t)(c0 + row) * R + r0 + col] = f2bf(tile[col][row]);
    }
}

// ---------------------------------------------------------------------------
// Prologue 2 (verified r13): Kp = Pk @ Wq via bf16 MFMA. grid 64 x 256.
// ---------------------------------------------------------------------------
__global__ __launch_bounds__(256) void kp_mfma_kernel(
        const float* __restrict__ Pk, const unsigned short* __restrict__ WqT,
        unsigned short* __restrict__ Kp) {
    const int tid = threadIdx.x;
    const int w   = tid >> 6;
    const int l   = tid & 63;
    const int lhi = l >> 4;
    const int llo = l & 15;
    const int N0  = blockIdx.x * 16;

    f32x4 acc = (f32x4){0.f, 0.f, 0.f, 0.f};

    for (int kb = 0; kb < 32; ++kb) {
        const int k0 = kb * 32 + lhi * 8;
        float4v p0 = *(const float4v*)(Pk + (size_t)(w * 16 + llo) * DD + k0);
        float4v p1 = *(const float4v*)(Pk + (size_t)(w * 16 + llo) * DD + k0 + 4);
        short8 a = pack_bf16x8(p0, p1);
        short8 b = *(const short8*)(WqT + (size_t)(N0 + llo) * DD + k0);
        acc = __builtin_amdgcn_mfma_f32_16x16x32_bf16(a, b, acc, 0, 0, 0);
    }
#pragma unroll
    for (int j = 0; j < 4; ++j) {
        const int t = w * 16 + lhi * 4 + j;
        Kp[(size_t)t * DD + N0 + llo] = f2bf(acc[j]);
    }
}

// ---------------------------------------------------------------------------
// Fused main (r10 verbatim — best measured: 80.8 µs total):
// grid 256 x 512 (8 waves), 128 q-rows/block (1 block/CU).
// Phase A: 16 K-steps of 64. 3-deep circular LDS bufs, global_load_lds for
//   A (x fp32 [128][64], 32 KB/step) and B (Kp bf16 [64][64], 8 KB/step);
//   counted s_waitcnt vmcnt(5) + raw s_barrier per step (T3/T4).
//   Wave (wr,wt): rows wr*64..+64, tokens wt*16..+16. Swizzle rule #21.
// Phase B: partial s -> sSf[128][68] (alias dead A-bufs) -> 4-lane shfl norm
//   -> exact GELU -> s' bf16 [128][128B] swizzled (alias dead B-bufs).
// Phase C: y = s' @ Pv swapped MFMA (D[m=d][n=q]); s'-frags in 64 VGPR,
//   PvT frags from L2; float4 stores. Wave w owns d-cols w*128..+128.
// ---------------------------------------------------------------------------
__global__ __launch_bounds__(512) void pattn_kernel(
        const float* __restrict__ x, const unsigned short* __restrict__ Kp,
        const unsigned short* __restrict__ PvT, float* __restrict__ out) {
    __shared__ __align__(16) unsigned char smem[122880];   // 3*32K (A) + 3*8K (B)

    const int tid = threadIdx.x;
    const int w   = tid >> 6;     // 0..7
    const int l   = tid & 63;
    const int lhi = l >> 4;       // 0..3
    const int llo = l & 15;       // 0..15
    const int wr  = w >> 2;       // 0..1  row-half
    const int wt  = w & 3;        // 0..3  token-slice
    const int R0  = blockIdx.x * 128;
    const char* xb  = (const char*)x;
    const char* kpb = (const char*)Kp;

    f32x4 acc[4];
#pragma unroll
    for (int rf = 0; rf < 4; ++rf) acc[rf] = (f32x4){0.f, 0.f, 0.f, 0.f};

#define ABUF(t) (smem + ((t) % 3) * 32768)
#define BBUF(t) (smem + 98304 + ((t) % 3) * 8192)

#define STAGE(t)                                                                \
    {                                                                           \
        unsigned char* abuf = ABUF(t);                                          \
        unsigned char* bbuf = BBUF(t);                                          \
        _Pragma("unroll")                                                       \
        for (int i = 0; i < 4; ++i) {                                           \
            const int row = i * 32 + w * 4 + (l >> 4);                          \
            const int csw = (l & 15) ^ ((row & 7) << 1);                        \
            gload_lds16(xb + (size_t)(R0 + row) * 4096 + (t) * 256 + csw * 16,  \
                        (void*)(abuf + (i * 32 + w * 4) * 256));                \
        }                                                                       \
        const int brow = w * 8 + (l >> 3);                                      \
        const int bcs  = (l & 7) ^ (brow & 7);                                  \
        gload_lds16(kpb + (size_t)brow * 2048 + (t) * 128 + bcs * 16,           \
                    (void*)(bbuf + (w * 8) * 128));                             \
    }

#define COMPUTE(t)                                                              \
    {                                                                           \
        unsigned char* abuf = ABUF(t);                                          \
        unsigned char* bbuf = BBUF(t);                                          \
        _Pragma("unroll")                                                       \
        for (int ks = 0; ks < 2; ++ks) {                                        \
            const int btok = wt * 16 + llo;                                     \
            const short8 bfrg = *(const short8*)(bbuf + btok * 128 +            \
                                  (((ks * 4 + lhi) ^ (btok & 7)) << 4));        \
            _Pragma("unroll")                                                   \
            for (int rf = 0; rf < 4; ++rf) {                                    \
                const int arow  = wr * 64 + rf * 16 + llo;                      \
                const int abyte = arow * 256 +                                  \
                                  (((ks * 4 + lhi) ^ (arow & 7)) << 5);         \
                const float4v f0 = *(const float4v*)(abuf + abyte);             \
                const float4v f1 = *(const float4v*)(abuf + abyte + 16);        \
                short8 a = pack_bf16x8(f0, f1);                                 \
                acc[rf] = __builtin_amdgcn_mfma_f32_16x16x32_bf16(a, bfrg, acc[rf], 0, 0, 0); \
            }                                                                   \
        }                                                                       \
    }

    // ---- Phase A: depth-3 pipeline, 2-step lookahead, counted vmcnt ----
    STAGE(0); STAGE(1);
#pragma unroll
    for (int t = 0; t < 16; ++t) {
        if (t < 15) { asm volatile("s_waitcnt vmcnt(5)" ::: "memory"); }
        else        { asm volatile("s_waitcnt vmcnt(0)" ::: "memory"); }
        __builtin_amdgcn_s_barrier();
        __builtin_amdgcn_sched_barrier(0);
        if (t < 14) STAGE(t + 2);
        COMPUTE(t);
    }
#undef STAGE
#undef COMPUTE
#undef ABUF
#undef BBUF

    __syncthreads();   // pipeline fully retired -> LDS free for aliases

    // ---- Phase B: partials -> sSf, 4-lane norm, exact GELU -> s' LDS ----
    float (*sSf)[68] = (float (*)[68])(void*)smem;          // [128][68] f32, 34.8 KB
#pragma unroll
    for (int rf = 0; rf < 4; ++rf)
#pragma unroll
        for (int j = 0; j < 4; ++j)
            sSf[wr * 64 + rf * 16 + lhi * 4 + j][wt * 16 + llo] = acc[rf][j];
    __syncthreads();

    unsigned char* sP = smem + 98304;                       // s' [128][128B] swizzled, 16 KB
    {
        const int r  = tid >> 2;          // 0..127 q-row
        const int tq = tid & 3;           // 16-token slice
        const f32x4 v0 = *(const f32x4*)&sSf[r][tq * 16];
        const f32x4 v1 = *(const f32x4*)&sSf[r][tq * 16 + 4];
        const f32x4 v2 = *(const f32x4*)&sSf[r][tq * 16 + 8];
        const f32x4 v3 = *(const f32x4*)&sSf[r][tq * 16 + 12];
        float ssq = v0.x*v0.x + v0.y*v0.y + v0.z*v0.z + v0.w*v0.w
                  + v1.x*v1.x + v1.y*v1.y + v1.z*v1.z + v1.w*v1.w
                  + v2.x*v2.x + v2.y*v2.y + v2.z*v2.z + v2.w*v2.w
                  + v3.x*v3.x + v3.y*v3.y + v3.z*v3.z + v3.w*v3.w;
        ssq += __shfl_xor(ssq, 1);
        ssq += __shfl_xor(ssq, 2);
        const float scale = 8.0f / sqrtf(ssq);
        short8 g0, g1;
#pragma unroll
        for (int k = 0; k < 4; ++k) {
            const float a0 = v0[k] * scale, a1 = v1[k] * scale;
            const float a2 = v2[k] * scale, a3 = v3[k] * scale;
            g0[k]     = (short)f2bf(0.5f * a0 * (1.0f + erff(a0 * 0.70710678118654752f)));
            g0[4 + k] = (short)f2bf(0.5f * a1 * (1.0f + erff(a1 * 0.70710678118654752f)));
            g1[k]     = (short)f2bf(0.5f * a2 * (1.0f + erff(a2 * 0.70710678118654752f)));
            g1[4 + k] = (short)f2bf(0.5f * a3 * (1.0f + erff(a3 * 0.70710678118654752f)));
        }
        // store token-chunks 2tq, 2tq+1 with chunk XOR (r&7)
        *(short8*)(sP + r * 128 + (((2 * tq)     ^ (r & 7)) << 4)) = g0;
        *(short8*)(sP + r * 128 + (((2 * tq + 1) ^ (r & 7)) << 4)) = g1;
    }
    __syncthreads();

    // ---- Phase C: y = s' @ Pv (swapped: D[m=d][n=q]); float4 stores ----
    short8 sfr[8][2];
#pragma unroll
    for (int qb = 0; qb < 8; ++qb)
#pragma unroll
        for (int ks = 0; ks < 2; ++ks) {
            const int q = qb * 16 + llo;
            sfr[qb][ks] = *(const short8*)(sP + q * 128 +
                              (((ks * 4 + lhi) ^ (q & 7)) << 4));
        }

    const int d0 = w * 128;
#pragma unroll 2
    for (int dt = 0; dt < 8; ++dt) {
        const unsigned short* ap = PvT + (size_t)(d0 + dt * 16 + llo) * 64 + lhi * 8;
        const short8 pa0 = *(const short8*)ap;
        const short8 pa1 = *(const short8*)(ap + 32);
#pragma unroll
        for (int qb = 0; qb < 8; ++qb) {
            f32x4 c2 = (f32x4){0.f, 0.f, 0.f, 0.f};
            c2 = __builtin_amdgcn_mfma_f32_16x16x32_bf16(pa0, sfr[qb][0], c2, 0, 0, 0);
            c2 = __builtin_amdgcn_mfma_f32_16x16x32_bf16(pa1, sfr[qb][1], c2, 0, 0, 0);
            *(float4v*)(out + (size_t)(R0 + qb * 16 + llo) * DD + d0 + dt * 16 + lhi * 4) = c2;
        }
    }
}

// ---------------------------------------------------------------------------
extern "C" void kernel_launch(void* const* d_in, const int* in_sizes, int n_in,
                              void* d_out, int out_size, void* d_ws, size_t ws_size,
                              hipStream_t stream) {
    (void)in_sizes; (void)n_in; (void)out_size; (void)ws_size;
    const float* x  = (const float*)d_in[0];
    const float* Wq = (const float*)d_in[1];
    const float* Pk = (const float*)d_in[2];
    const float* Pv = (const float*)d_in[3];
    float* out = (float*)d_out;

    // ws layout (2.25 MB total):
    //   WqT bf16 [1024][1024] @ 0            (2 MB)
    //   Kp  bf16 [64][1024]   @ 2 MB         (128 KB)
    //   PvT bf16 [1024][64]   @ 2 MB + 128K  (128 KB)
    unsigned short* WqT = (unsigned short*)d_ws;
    unsigned short* Kp  = (unsigned short*)((char*)d_ws + 2097152);
    unsigned short* PvT = (unsigned short*)((char*)d_ws + 2097152 + 131072);

    prep_transpose_kernel<<<272, 256, 0, stream>>>(Wq, Pv, WqT, PvT);
    kp_mfma_kernel<<<64, 256, 0, stream>>>(Pk, WqT, Kp);
    pattn_kernel<<<256, 512, 0, stream>>>(x, Kp, PvT, out);
}

// Round 18
// 59.340 us; speedup vs baseline: 1.9119x; 1.1902x over previous
//
#include <hip/hip_runtime.h>
#include <hip/hip_bf16.h>
#include <math.h>

// Shapes
#define QL 32768
#define DD 1024
#define NTOK 64

using short8   = __attribute__((ext_vector_type(8))) short;
using f32x4    = __attribute__((ext_vector_type(4))) float;
using float4v  = __attribute__((ext_vector_type(4))) float;
using ushort4v = __attribute__((ext_vector_type(4))) unsigned short;

// RNE f32->bf16 via bit trick (exact RNE)
__device__ __forceinline__ unsigned short f2bf(float f) {
    unsigned int u = __float_as_uint(f);
    unsigned int r = (u + 0x7FFFu + ((u >> 16) & 1u)) >> 16;
    return (unsigned short)r;
}

__device__ __forceinline__ short8 pack_bf16x8(float4v lo, float4v hi) {
    short8 a;
    ((__hip_bfloat162*)&a)[0] = __float22bfloat162_rn(float2{lo.x, lo.y});
    ((__hip_bfloat162*)&a)[1] = __float22bfloat162_rn(float2{lo.z, lo.w});
    ((__hip_bfloat162*)&a)[2] = __float22bfloat162_rn(float2{hi.x, hi.y});
    ((__hip_bfloat162*)&a)[3] = __float22bfloat162_rn(float2{hi.z, hi.w});
    return a;
}

// async global->LDS, 16B per lane; dest = wave-uniform base + lane*16
__device__ __forceinline__ void gload_lds16(const void* g, void* l) {
    __builtin_amdgcn_global_load_lds(
        (const __attribute__((address_space(1))) void*)g,
        (__attribute__((address_space(3))) void*)l,
        16, 0, 0);
}

// ---------------------------------------------------------------------------
// Merged prologue: ONE launch, grid 80 x 256.
// Blocks 0..63: Kp[:, b*16..b*16+16] = Pk @ Wq.
//   Stage Wq columns N0..N0+16 into LDS transposed (wqt[e][d] bf16, stride
//   1048 elem = 2096 B: 16B-aligned rows, e-groups spread across banks),
//   then the r13-VERIFIED MFMA loop with B-frags read from LDS.
// Blocks 64..79: PvT[e][t] = bf16(Pv[t][e])  (verified transpose path).
// ---------------------------------------------------------------------------
#define WQT_STRIDE 1048   // elements; 2096 B per e-row, 16B aligned
__global__ __launch_bounds__(256) void kpv_kernel(
        const float* __restrict__ Wq, const float* __restrict__ Pk,
        const float* __restrict__ Pv,
        unsigned short* __restrict__ Kp, unsigned short* __restrict__ PvT) {
    __shared__ __align__(16) unsigned char sm[16 * WQT_STRIDE * 2];  // 33536 B
    const int tid = threadIdx.x;

    if (blockIdx.x < 64) {
        const int N0 = blockIdx.x * 16;
        unsigned short* wqt = (unsigned short*)sm;   // [16 e][WQT_STRIDE d]

        // stage: 16 passes x (64 rows x 16 cols); 4 threads cover one row's 64 B
        const int c4 = (tid & 3) * 4;
#pragma unroll
        for (int p = 0; p < 16; ++p) {
            const int row = p * 64 + (tid >> 2);     // d index 0..1023
            const float4v v = *(const float4v*)(Wq + (size_t)row * DD + N0 + c4);
#pragma unroll
            for (int k = 0; k < 4; ++k)
                wqt[(size_t)(c4 + k) * WQT_STRIDE + row] = f2bf(v[k]);
        }
        __syncthreads();

        // verified kp_mfma loop; B-frag now from LDS
        const int w   = tid >> 6;
        const int l   = tid & 63;
        const int lhi = l >> 4;
        const int llo = l & 15;

        f32x4 acc = (f32x4){0.f, 0.f, 0.f, 0.f};
        for (int kb = 0; kb < 32; ++kb) {
            const int k0 = kb * 32 + lhi * 8;
            float4v p0 = *(const float4v*)(Pk + (size_t)(w * 16 + llo) * DD + k0);
            float4v p1 = *(const float4v*)(Pk + (size_t)(w * 16 + llo) * DD + k0 + 4);
            short8 a = pack_bf16x8(p0, p1);
            short8 b = *(const short8*)(wqt + (size_t)llo * WQT_STRIDE + k0);
            acc = __builtin_amdgcn_mfma_f32_16x16x32_bf16(a, b, acc, 0, 0, 0);
        }
#pragma unroll
        for (int j = 0; j < 4; ++j) {
            const int t = w * 16 + lhi * 4 + j;
            Kp[(size_t)t * DD + N0 + llo] = f2bf(acc[j]);
        }
    } else {
        // Pv transpose (verified): c0 = 64-col stripe
        float (*tile)[65] = (float (*)[65])(void*)sm;    // 16640 B <= 33536
        const int c0 = (blockIdx.x - 64) * 64;
#pragma unroll
        for (int i = 0; i < 16; ++i) {
            const int lin = tid + 256 * i;
            const int row = lin >> 6, col = lin & 63;
            tile[row][col] = Pv[(size_t)row * DD + c0 + col];
        }
        __syncthreads();
#pragma unroll
        for (int i = 0; i < 16; ++i) {
            const int lin = tid + 256 * i;
            const int row = lin >> 6, col = lin & 63;
            PvT[(size_t)(c0 + row) * 64 + col] = f2bf(tile[col][row]);
        }
    }
}

// ---------------------------------------------------------------------------
// Fused main (r10/r17 verbatim — best measured):
// grid 256 x 512 (8 waves), 128 q-rows/block (1 block/CU).
// Phase A: 16 K-steps of 64. 3-deep circular LDS bufs, global_load_lds for
//   A (x fp32 [128][64], 32 KB/step) and B (Kp bf16 [64][64], 8 KB/step);
//   counted s_waitcnt vmcnt(5) + raw s_barrier per step (T3/T4).
// Phase B: partial s -> sSf[128][68] (alias dead A-bufs) -> 4-lane shfl norm
//   -> exact GELU -> s' bf16 [128][128B] swizzled (alias dead B-bufs).
// Phase C: y = s' @ Pv swapped MFMA (D[m=d][n=q]); s'-frags in 64 VGPR,
//   PvT frags from L2; float4 stores. Wave w owns d-cols w*128..+128.
// ---------------------------------------------------------------------------
__global__ __launch_bounds__(512) void pattn_kernel(
        const float* __restrict__ x, const unsigned short* __restrict__ Kp,
        const unsigned short* __restrict__ PvT, float* __restrict__ out) {
    __shared__ __align__(16) unsigned char smem[122880];   // 3*32K (A) + 3*8K (B)

    const int tid = threadIdx.x;
    const int w   = tid >> 6;     // 0..7
    const int l   = tid & 63;
    const int lhi = l >> 4;       // 0..3
    const int llo = l & 15;       // 0..15
    const int wr  = w >> 2;       // 0..1  row-half
    const int wt  = w & 3;        // 0..3  token-slice
    const int R0  = blockIdx.x * 128;
    const char* xb  = (const char*)x;
    const char* kpb = (const char*)Kp;

    f32x4 acc[4];
#pragma unroll
    for (int rf = 0; rf < 4; ++rf) acc[rf] = (f32x4){0.f, 0.f, 0.f, 0.f};

#define ABUF(t) (smem + ((t) % 3) * 32768)
#define BBUF(t) (smem + 98304 + ((t) % 3) * 8192)

#define STAGE(t)                                                                \
    {                                                                           \
        unsigned char* abuf = ABUF(t);                                          \
        unsigned char* bbuf = BBUF(t);                                          \
        _Pragma("unroll")                                                       \
        for (int i = 0; i < 4; ++i) {                                           \
            const int row = i * 32 + w * 4 + (l >> 4);                          \
            const int csw = (l & 15) ^ ((row & 7) << 1);                        \
            gload_lds16(xb + (size_t)(R0 + row) * 4096 + (t) * 256 + csw * 16,  \
                        (void*)(abuf + (i * 32 + w * 4) * 256));                \
        }                                                                       \
        const int brow = w * 8 + (l >> 3);                                      \
        const int bcs  = (l & 7) ^ (brow & 7);                                  \
        gload_lds16(kpb + (size_t)brow * 2048 + (t) * 128 + bcs * 16,           \
                    (void*)(bbuf + (w * 8) * 128));                             \
    }

#define COMPUTE(t)                                                              \
    {                                                                           \
        unsigned char* abuf = ABUF(t);                                          \
        unsigned char* bbuf = BBUF(t);                                          \
        _Pragma("unroll")                                                       \
        for (int ks = 0; ks < 2; ++ks) {                                        \
            const int btok = wt * 16 + llo;                                     \
            const short8 bfrg = *(const short8*)(bbuf + btok * 128 +            \
                                  (((ks * 4 + lhi) ^ (btok & 7)) << 4));        \
            _Pragma("unroll")                                                   \
            for (int rf = 0; rf < 4; ++rf) {                                    \
                const int arow  = wr * 64 + rf * 16 + llo;                      \
                const int abyte = arow * 256 +                                  \
                                  (((ks * 4 + lhi) ^ (arow & 7)) << 5);         \
                const float4v f0 = *(const float4v*)(abuf + abyte);             \
                const float4v f1 = *(const float4v*)(abuf + abyte + 16);        \
                short8 a = pack_bf16x8(f0, f1);                                 \
                acc[rf] = __builtin_amdgcn_mfma_f32_16x16x32_bf16(a, bfrg, acc[rf], 0, 0, 0); \
            }                                                                   \
        }                                                                       \
    }

    // ---- Phase A: depth-3 pipeline, 2-step lookahead, counted vmcnt ----
    STAGE(0); STAGE(1);
#pragma unroll
    for (int t = 0; t < 16; ++t) {
        if (t < 15) { asm volatile("s_waitcnt vmcnt(5)" ::: "memory"); }
        else        { asm volatile("s_waitcnt vmcnt(0)" ::: "memory"); }
        __builtin_amdgcn_s_barrier();
        __builtin_amdgcn_sched_barrier(0);
        if (t < 14) STAGE(t + 2);
        COMPUTE(t);
    }
#undef STAGE
#undef COMPUTE
#undef ABUF
#undef BBUF

    __syncthreads();   // pipeline fully retired -> LDS free for aliases

    // ---- Phase B: partials -> sSf, 4-lane norm, exact GELU -> s' LDS ----
    float (*sSf)[68] = (float (*)[68])(void*)smem;          // [128][68] f32, 34.8 KB
#pragma unroll
    for (int rf = 0; rf < 4; ++rf)
#pragma unroll
        for (int j = 0; j < 4; ++j)
            sSf[wr * 64 + rf * 16 + lhi * 4 + j][wt * 16 + llo] = acc[rf][j];
    __syncthreads();

    unsigned char* sP = smem + 98304;                       // s' [128][128B] swizzled, 16 KB
    {
        const int r  = tid >> 2;          // 0..127 q-row
        const int tq = tid & 3;           // 16-token slice
        const f32x4 v0 = *(const f32x4*)&sSf[r][tq * 16];
        const f32x4 v1 = *(const f32x4*)&sSf[r][tq * 16 + 4];
        const f32x4 v2 = *(const f32x4*)&sSf[r][tq * 16 + 8];
        const f32x4 v3 = *(const f32x4*)&sSf[r][tq * 16 + 12];
        float ssq = v0.x*v0.x + v0.y*v0.y + v0.z*v0.z + v0.w*v0.w
                  + v1.x*v1.x + v1.y*v1.y + v1.z*v1.z + v1.w*v1.w
                  + v2.x*v2.x + v2.y*v2.y + v2.z*v2.z + v2.w*v2.w
                  + v3.x*v3.x + v3.y*v3.y + v3.z*v3.z + v3.w*v3.w;
        ssq += __shfl_xor(ssq, 1);
        ssq += __shfl_xor(ssq, 2);
        const float scale = 8.0f / sqrtf(ssq);
        short8 g0, g1;
#pragma unroll
        for (int k = 0; k < 4; ++k) {
            const float a0 = v0[k] * scale, a1 = v1[k] * scale;
            const float a2 = v2[k] * scale, a3 = v3[k] * scale;
            g0[k]     = (short)f2bf(0.5f * a0 * (1.0f + erff(a0 * 0.70710678118654752f)));
            g0[4 + k] = (short)f2bf(0.5f * a1 * (1.0f + erff(a1 * 0.70710678118654752f)));
            g1[k]     = (short)f2bf(0.5f * a2 * (1.0f + erff(a2 * 0.70710678118654752f)));
            g1[4 + k] = (short)f2bf(0.5f * a3 * (1.0f + erff(a3 * 0.70710678118654752f)));
        }
        *(short8*)(sP + r * 128 + (((2 * tq)     ^ (r & 7)) << 4)) = g0;
        *(short8*)(sP + r * 128 + (((2 * tq + 1) ^ (r & 7)) << 4)) = g1;
    }
    __syncthreads();

    // ---- Phase C: y = s' @ Pv (swapped: D[m=d][n=q]); float4 stores ----
    short8 sfr[8][2];
#pragma unroll
    for (int qb = 0; qb < 8; ++qb)
#pragma unroll
        for (int ks = 0; ks < 2; ++ks) {
            const int q = qb * 16 + llo;
            sfr[qb][ks] = *(const short8*)(sP + q * 128 +
                              (((ks * 4 + lhi) ^ (q & 7)) << 4));
        }

    const int d0 = w * 128;
#pragma unroll 2
    for (int dt = 0; dt < 8; ++dt) {
        const unsigned short* ap = PvT + (size_t)(d0 + dt * 16 + llo) * 64 + lhi * 8;
        const short8 pa0 = *(const short8*)ap;
        const short8 pa1 = *(const short8*)(ap + 32);
#pragma unroll
        for (int qb = 0; qb < 8; ++qb) {
            f32x4 c2 = (f32x4){0.f, 0.f, 0.f, 0.f};
            c2 = __builtin_amdgcn_mfma_f32_16x16x32_bf16(pa0, sfr[qb][0], c2, 0, 0, 0);
            c2 = __builtin_amdgcn_mfma_f32_16x16x32_bf16(pa1, sfr[qb][1], c2, 0, 0, 0);
            *(float4v*)(out + (size_t)(R0 + qb * 16 + llo) * DD + d0 + dt * 16 + lhi * 4) = c2;
        }
    }
}

// ---------------------------------------------------------------------------
extern "C" void kernel_launch(void* const* d_in, const int* in_sizes, int n_in,
                              void* d_out, int out_size, void* d_ws, size_t ws_size,
                              hipStream_t stream) {
    (void)in_sizes; (void)n_in; (void)out_size; (void)ws_size;
    const float* x  = (const float*)d_in[0];
    const float* Wq = (const float*)d_in[1];
    const float* Pk = (const float*)d_in[2];
    const float* Pv = (const float*)d_in[3];
    float* out = (float*)d_out;

    // ws layout (256 KB): Kp bf16 [64][1024] @ 0; PvT bf16 [1024][64] @ 128K
    unsigned short* Kp  = (unsigned short*)d_ws;
    unsigned short* PvT = (unsigned short*)((char*)d_ws + 131072);

    kpv_kernel<<<80, 256, 0, stream>>>(Wq, Pk, Pv, Kp, PvT);
    pattn_kernel<<<256, 512, 0, stream>>>(x, Kp, PvT, out);
}